// Round 2
// baseline (18342.049 us; speedup 1.0000x reference)
//
#include <hip/hip_runtime.h>

#define DEVINL __device__ __forceinline__

namespace {
constexpr int B = 256, T = 128, F = 128, H = 512;
constexpr int NBLK = 256;

// workspace layout (float offsets)
constexpr size_t OFF_AT  = 0;                          // [2F][B] rows 0..127 = c_c^T, 128..255 = m^T
constexpr size_t OFF_HA  = OFF_AT + (size_t)2 * F * B; // h ping  [H][B]
constexpr size_t OFF_HB  = OFF_HA + (size_t)H * B;     // h pong  [H][B]
constexpr size_t OFF_CT  = OFF_HB + (size_t)H * B;     // LSTM c  [H][B]
constexpr size_t OFF_NUM = OFF_CT + (size_t)H * B;     // [T] loss numerators
constexpr size_t OFF_DEN = OFF_NUM + T;                // [T] denominators
constexpr size_t OFF_BAR = OFF_DEN + T;                // barrier cnt/gen (+pad)
constexpr size_t OFF_XH  = OFF_BAR + 16;               // x_hist^T [F][B]
constexpr size_t OFF_XC  = OFF_XH + (size_t)F * B;     // x_c^T    [F][B]
constexpr size_t OFF_GX  = OFF_XC + (size_t)F * B;     // gamma_x^T[F][B]
constexpr size_t OFF_WG  = OFF_GX + (size_t)F * B;     // gathered gate weights [H][768][4]
constexpr size_t WS_FLOATS = OFF_WG + (size_t)H * 768 * 4;
constexpr size_t ZERO_BYTES = OFF_XH * sizeof(float);  // zero AT,hA,hB,cT,num,den,bar
constexpr unsigned SPIN_CAP = 100000u;                 // hang tripwire (~5 ms/barrier max)
}

DEVINL float fast_sig(float x)  { return 1.f / (1.f + __expf(-x)); }
DEVINL float fast_tanh(float x) { return 1.f - 2.f / (1.f + __expf(2.f * x)); } // no-overflow form

DEVINL float wave_sum(float v) {
#pragma unroll
  for (int s = 32; s; s >>= 1) v += __shfl_down(v, s, 64);
  return v;
}

// sense-reversing grid barrier; device-scope fences for cross-XCD visibility.
// SPIN_CAP converts a (theoretically impossible) residency deadlock into a
// bounded-time wrong-answer instead of a GPU hang that kills the container.
DEVINL void grid_bar(unsigned* bar) {
  __syncthreads();
  if (threadIdx.x == 0) {
    __builtin_amdgcn_fence(__ATOMIC_RELEASE, "agent");
    unsigned g0 = __hip_atomic_load(bar + 1, __ATOMIC_RELAXED, __HIP_MEMORY_SCOPE_AGENT);
    unsigned a  = __hip_atomic_fetch_add(bar, 1u, __ATOMIC_RELAXED, __HIP_MEMORY_SCOPE_AGENT);
    if (a == (unsigned)(NBLK - 1)) {
      __hip_atomic_store(bar, 0u, __ATOMIC_RELAXED, __HIP_MEMORY_SCOPE_AGENT);
      __hip_atomic_store(bar + 1, g0 + 1u, __ATOMIC_RELEASE, __HIP_MEMORY_SCOPE_AGENT);
    } else {
      unsigned spins = 0;
      while (__hip_atomic_load(bar + 1, __ATOMIC_RELAXED, __HIP_MEMORY_SCOPE_AGENT) == g0) {
        __builtin_amdgcn_s_sleep(2);
        if (++spins > SPIN_CAP) break;   // tripwire: desync > dead container
      }
    }
    __builtin_amdgcn_fence(__ATOMIC_ACQUIRE, "agent");
  }
  __syncthreads();
}

// Gather W_ih|W_hh into [unit j][k 0..767][gate i,f,g,o] so the P4 inner loop
// fetches one wave-uniform float4 per unit per k (scalarizes to s_load_dwordx4).
__global__ void prep_wg(const float* __restrict__ Wih, const float* __restrict__ Whh,
                        float* __restrict__ Wg) {
  const int j = blockIdx.x;
  for (int k = threadIdx.x; k < 768; k += blockDim.x) {
    float4 v;
    if (k < 2 * F) {
      v.x = Wih[(0 * H + j) * (2 * F) + k];
      v.y = Wih[(1 * H + j) * (2 * F) + k];
      v.z = Wih[(2 * H + j) * (2 * F) + k];
      v.w = Wih[(3 * H + j) * (2 * F) + k];
    } else {
      const int kk = k - 2 * F;
      v.x = Whh[(0 * H + j) * H + kk];
      v.y = Whh[(1 * H + j) * H + kk];
      v.z = Whh[(2 * H + j) * H + kk];
      v.w = Whh[(3 * H + j) * H + kk];
    }
    *(float4*)(Wg + ((size_t)j * 768 + k) * 4) = v;
  }
}

__global__ void __launch_bounds__(256) rits_main(
    const float* __restrict__ x, const float* __restrict__ m, const float* __restrict__ d,
    const float* __restrict__ tx, const float* __restrict__ tmask,
    const float* __restrict__ td_h_W, const float* __restrict__ td_h_b,
    const float* __restrict__ td_x_W, const float* __restrict__ td_x_b,
    const float* __restrict__ hist_W, const float* __restrict__ hist_b,
    const float* __restrict__ feat_W, const float* __restrict__ feat_b,
    const float* __restrict__ wc_W, const float* __restrict__ wc_b,
    const float* __restrict__ b_ih, const float* __restrict__ b_hh,
    float* __restrict__ ws, float* __restrict__ out)
{
  const int g = blockIdx.x;
  const int tid = threadIdx.x;   // = batch row in P2/P3/P4 inner loops

  float* AT  = ws + OFF_AT;
  float* hA  = ws + OFF_HA;
  float* hB  = ws + OFF_HB;
  float* cT  = ws + OFF_CT;
  float* num = ws + OFF_NUM;
  float* den = ws + OFF_DEN;
  unsigned* bar = (unsigned*)(ws + OFF_BAR);
  float* xhT = ws + OFF_XH;
  float* xcT = ws + OFF_XC;
  float* gxT = ws + OFF_GX;
  const float* Wg = ws + OFF_WG;

  __shared__ float redA[4], redB[4];

  const int j0 = 2 * g, j1 = 2 * g + 1;   // this block's H units (P4)

  for (int t = 0; t < T; ++t) {
    const float* hRd = (t & 1) ? hB : hA;   // decayed h(t), written by P4(t-1)
    float*       hWr = (t & 1) ? hA : hB;

    grid_bar(bar);   // h(t) fully published

    // ---------- P2: x_hist, x_c, gamma_x, m^T, loss term 1, denom ----------
    if (g < F) {
      const int f = g;
      const float* w = hist_W + (size_t)f * H;
      float acc = hist_b[f];
#pragma unroll 8
      for (int k = 0; k < H; ++k) acc = fmaf(hRd[k * B + tid], w[k], acc); // coalesced, w scalarizes
      const int idx = (tid * T + t) * F + f;
      const float mv = m[idx], xv = x[idx], dv = d[idx];
      xhT[f * B + tid] = acc;
      const float xc = mv * xv + (1.f - mv) * acc;
      xcT[f * B + tid] = xc;
      gxT[f * B + tid] = __expf(-fmaxf(fmaf(dv, td_x_W[f * F + f], td_x_b[f]), 0.f));
      AT[(F + f) * B + tid] = mv;
      const float ev = tmask[idx], tg = tx[idx];
      const float d1 = acc - tg;
      float s1 = wave_sum(d1 * d1 * ev), s2 = wave_sum(ev);
      if ((tid & 63) == 0) { redA[tid >> 6] = s1; redB[tid >> 6] = s2; }
      __syncthreads();
      if (tid == 0) {
        atomicAdd(&num[t], redA[0] + redA[1] + redA[2] + redA[3]);
        atomicAdd(&den[t], redB[0] + redB[1] + redB[2] + redB[3]);
      }
    }

    grid_bar(bar);   // x_c complete

    // ---------- P3: z_h, alpha, c_h, c_c (imputation), loss terms 2+3 ----------
    if (g < F) {
      const int f = g;
      const float* fw = feat_W + (size_t)f * F;
      float acc = feat_b[f];
#pragma unroll 8
      for (int k = 0; k < F; ++k) acc = fmaf(xcT[k * B + tid], fw[k], acc);
      acc -= xcT[f * B + tid] * fw[f];           // diagonal mask
      const float zh = acc;
      const float* wcw = wc_W + (size_t)f * (2 * F);
      float aacc = wc_b[f];
#pragma unroll 8
      for (int k = 0; k < F; ++k) {
        aacc = fmaf(gxT[k * B + tid], wcw[k], aacc);
        aacc = fmaf(AT[(F + k) * B + tid], wcw[F + k], aacc);
      }
      const float al = fast_sig(aacc);
      const float xh = xhT[f * B + tid];
      const float ch = al * zh + (1.f - al) * xh;
      const int idx = (tid * T + t) * F + f;
      const float mv = AT[(F + f) * B + tid];
      const float cc = mv * x[idx] + (1.f - mv) * ch;
      AT[f * B + tid] = cc;
      out[idx] = cc;                              // imputation
      const float ev = tmask[idx], tg = tx[idx];
      const float d2 = zh - tg, d3 = ch - tg;
      float s = wave_sum((d2 * d2 + d3 * d3) * ev);
      if ((tid & 63) == 0) redA[tid >> 6] = s;
      __syncthreads();
      if (tid == 0) atomicAdd(&num[t], redA[0] + redA[1] + redA[2] + redA[3]);
    }

    grid_bar(bar);   // c_c complete

    // ---------- P4: gates (K=768), LSTM update, next-step decay (own 2 units) ----------
    {
      const float4* wg0 = (const float4*)(Wg + (size_t)j0 * 768 * 4);
      const float4* wg1 = (const float4*)(Wg + (size_t)j1 * 768 * 4);
      float a0i = b_ih[j0] + b_hh[j0];
      float a0f = b_ih[H + j0] + b_hh[H + j0];
      float a0g = b_ih[2 * H + j0] + b_hh[2 * H + j0];
      float a0o = b_ih[3 * H + j0] + b_hh[3 * H + j0];
      float a1i = b_ih[j1] + b_hh[j1];
      float a1f = b_ih[H + j1] + b_hh[H + j1];
      float a1g = b_ih[2 * H + j1] + b_hh[2 * H + j1];
      float a1o = b_ih[3 * H + j1] + b_hh[3 * H + j1];
#pragma unroll 4
      for (int k = 0; k < 2 * F; ++k) {          // [c_c | m] part
        const float a = AT[k * B + tid];
        const float4 w0 = wg0[k], w1 = wg1[k];
        a0i = fmaf(a, w0.x, a0i); a0f = fmaf(a, w0.y, a0f);
        a0g = fmaf(a, w0.z, a0g); a0o = fmaf(a, w0.w, a0o);
        a1i = fmaf(a, w1.x, a1i); a1f = fmaf(a, w1.y, a1f);
        a1g = fmaf(a, w1.z, a1g); a1o = fmaf(a, w1.w, a1o);
      }
#pragma unroll 4
      for (int k = 0; k < H; ++k) {              // h part
        const float a = hRd[k * B + tid];
        const float4 w0 = wg0[2 * F + k], w1 = wg1[2 * F + k];
        a0i = fmaf(a, w0.x, a0i); a0f = fmaf(a, w0.y, a0f);
        a0g = fmaf(a, w0.z, a0g); a0o = fmaf(a, w0.w, a0o);
        a1i = fmaf(a, w1.x, a1i); a1f = fmaf(a, w1.y, a1f);
        a1g = fmaf(a, w1.z, a1g); a1o = fmaf(a, w1.w, a1o);
      }
      // gamma_h(t+1) for own units (folds old P1 into epilogue; enables h double-buffer)
      const int t2 = (t + 1 < T) ? (t + 1) : t;
      const float* drow = d + (tid * T + t2) * F;
      const float* w0r = td_h_W + (size_t)j0 * F;
      const float* w1r = td_h_W + (size_t)j1 * F;
      float g0acc = td_h_b[j0], g1acc = td_h_b[j1];
#pragma unroll 4
      for (int k = 0; k < F; ++k) {
        const float dv = drow[k];
        g0acc = fmaf(dv, w0r[k], g0acc);
        g1acc = fmaf(dv, w1r[k], g1acc);
      }
      const float gam0 = __expf(-fmaxf(g0acc, 0.f));
      const float gam1 = __expf(-fmaxf(g1acc, 0.f));
      {
        const float ig = fast_sig(a0i), fg = fast_sig(a0f);
        const float gg = fast_tanh(a0g), og = fast_sig(a0o);
        const float cn = fg * cT[j0 * B + tid] + ig * gg;
        const float hn = og * fast_tanh(cn);
        cT[j0 * B + tid] = cn;
        hWr[j0 * B + tid] = hn * gam0;           // store pre-decayed h(t+1)
      }
      {
        const float ig = fast_sig(a1i), fg = fast_sig(a1f);
        const float gg = fast_tanh(a1g), og = fast_sig(a1o);
        const float cn = fg * cT[j1 * B + tid] + ig * gg;
        const float hn = og * fast_tanh(cn);
        cT[j1 * B + tid] = cn;
        hWr[j1 * B + tid] = hn * gam1;
      }
    }
  }

  grid_bar(bar);
  if (g == 0 && tid == 0) {
    float L = 0.f;
    for (int t = 0; t < T; ++t) L += num[t] / (den[t] + 1e-8f);
    out[(size_t)B * T * F] = L / (float)T;
  }
}

extern "C" void kernel_launch(void* const* d_in, const int* in_sizes, int n_in,
                              void* d_out, int out_size, void* d_ws, size_t ws_size,
                              hipStream_t stream) {
  const float* x      = (const float*)d_in[0];
  const float* m      = (const float*)d_in[1];
  const float* d      = (const float*)d_in[2];
  const float* tx     = (const float*)d_in[3];
  const float* tmask  = (const float*)d_in[4];
  const float* td_h_W = (const float*)d_in[5];
  const float* td_h_b = (const float*)d_in[6];
  const float* td_x_W = (const float*)d_in[7];
  const float* td_x_b = (const float*)d_in[8];
  const float* hist_W = (const float*)d_in[9];
  const float* hist_b = (const float*)d_in[10];
  const float* feat_W = (const float*)d_in[11];
  const float* feat_b = (const float*)d_in[12];
  const float* wc_W   = (const float*)d_in[13];
  const float* wc_b   = (const float*)d_in[14];
  const float* W_ih   = (const float*)d_in[15];
  const float* W_hh   = (const float*)d_in[16];
  const float* b_ih   = (const float*)d_in[17];
  const float* b_hh   = (const float*)d_in[18];

  float* ws  = (float*)d_ws;
  float* out = (float*)d_out;

  // Tripwire: if the harness workspace is smaller than our layout, launching
  // would write OOB and can kill the container. Skip instead -> clean absmax
  // failure whose signature (absmax ~= 5, zero output) identifies this cause.
  if (ws_size < WS_FLOATS * sizeof(float)) return;

  // zero h/c state, loss accumulators, barrier (ws is 0xAA-poisoned each launch)
  hipMemsetAsync(d_ws, 0, ZERO_BYTES, stream);
  prep_wg<<<dim3(H), dim3(256), 0, stream>>>(W_ih, W_hh, ws + OFF_WG);
  rits_main<<<dim3(NBLK), dim3(256), 0, stream>>>(
      x, m, d, tx, tmask, td_h_W, td_h_b, td_x_W, td_x_b,
      hist_W, hist_b, feat_W, feat_b, wc_W, wc_b, b_ih, b_hh, ws, out);
}

// Round 3
// 15346.660 us; speedup vs baseline: 1.1952x; 1.1952x over previous
//
#include <hip/hip_runtime.h>

#define DEVINL __device__ __forceinline__

namespace {
constexpr int B = 256, T = 128, F = 128, H = 512;
constexpr int NBLK = 256;

// workspace layout (float offsets)
constexpr size_t OFF_AT  = 0;                          // [2F][B] rows 0..127 = c_c^T, 128..255 = m^T
constexpr size_t OFF_HA  = OFF_AT + (size_t)2 * F * B; // h ping  [H][B]
constexpr size_t OFF_HB  = OFF_HA + (size_t)H * B;     // h pong  [H][B]
constexpr size_t OFF_CT  = OFF_HB + (size_t)H * B;     // LSTM c  [H][B]
constexpr size_t OFF_NUM = OFF_CT + (size_t)H * B;     // [T] loss numerators
constexpr size_t OFF_DEN = OFF_NUM + T;                // [T] denominators
constexpr size_t OFF_BAR = OFF_DEN + T;                // barrier cnt/gen (+pad)
constexpr size_t OFF_XH  = OFF_BAR + 16;               // x_hist^T [F][B]
constexpr size_t OFF_XC  = OFF_XH + (size_t)F * B;     // x_c^T    [F][B]
constexpr size_t OFF_GX  = OFF_XC + (size_t)F * B;     // gamma_x^T[F][B]
constexpr size_t OFF_WG  = OFF_GX + (size_t)F * B;     // gathered gate weights [H][768][4]
constexpr size_t WS_FLOATS = OFF_WG + (size_t)H * 768 * 4;
constexpr size_t ZERO_BYTES = OFF_XH * sizeof(float);  // zero AT,hA,hB,cT,num,den,bar
constexpr unsigned SPIN_CAP = 100000u;                 // hang tripwire
}

DEVINL float fast_sig(float x)  { return 1.f / (1.f + __expf(-x)); }
DEVINL float fast_tanh(float x) { return 1.f - 2.f / (1.f + __expf(2.f * x)); } // no-overflow form

DEVINL float wave_sum(float v) {
#pragma unroll
  for (int s = 32; s; s >>= 1) v += __shfl_down(v, s, 64);
  return v;
}

// sense-reversing grid barrier; device-scope fences for cross-XCD visibility.
DEVINL void grid_bar(unsigned* bar) {
  __syncthreads();
  if (threadIdx.x == 0) {
    __builtin_amdgcn_fence(__ATOMIC_RELEASE, "agent");
    unsigned g0 = __hip_atomic_load(bar + 1, __ATOMIC_RELAXED, __HIP_MEMORY_SCOPE_AGENT);
    unsigned a  = __hip_atomic_fetch_add(bar, 1u, __ATOMIC_RELAXED, __HIP_MEMORY_SCOPE_AGENT);
    if (a == (unsigned)(NBLK - 1)) {
      __hip_atomic_store(bar, 0u, __ATOMIC_RELAXED, __HIP_MEMORY_SCOPE_AGENT);
      __hip_atomic_store(bar + 1, g0 + 1u, __ATOMIC_RELEASE, __HIP_MEMORY_SCOPE_AGENT);
    } else {
      unsigned spins = 0;
      while (__hip_atomic_load(bar + 1, __ATOMIC_RELAXED, __HIP_MEMORY_SCOPE_AGENT) == g0) {
        __builtin_amdgcn_s_sleep(2);
        if (++spins > SPIN_CAP) break;   // tripwire: desync > dead container
      }
    }
    __builtin_amdgcn_fence(__ATOMIC_ACQUIRE, "agent");
  }
  __syncthreads();
}

// Gather W_ih|W_hh into [unit j][k 0..767][gate i,f,g,o].
__global__ void prep_wg(const float* __restrict__ Wih, const float* __restrict__ Whh,
                        float* __restrict__ Wg) {
  const int j = blockIdx.x;
  for (int k = threadIdx.x; k < 768; k += blockDim.x) {
    float4 v;
    if (k < 2 * F) {
      v.x = Wih[(0 * H + j) * (2 * F) + k];
      v.y = Wih[(1 * H + j) * (2 * F) + k];
      v.z = Wih[(2 * H + j) * (2 * F) + k];
      v.w = Wih[(3 * H + j) * (2 * F) + k];
    } else {
      const int kk = k - 2 * F;
      v.x = Whh[(0 * H + j) * H + kk];
      v.y = Whh[(1 * H + j) * H + kk];
      v.z = Whh[(2 * H + j) * H + kk];
      v.w = Whh[(3 * H + j) * H + kk];
    }
    *(float4*)(Wg + ((size_t)j * 768 + k) * 4) = v;
  }
}

__global__ void __launch_bounds__(256) rits_main(
    const float* __restrict__ x, const float* __restrict__ m, const float* __restrict__ d,
    const float* __restrict__ tx, const float* __restrict__ tmask,
    const float* __restrict__ td_h_W, const float* __restrict__ td_h_b,
    const float* __restrict__ td_x_W, const float* __restrict__ td_x_b,
    const float* __restrict__ hist_W, const float* __restrict__ hist_b,
    const float* __restrict__ feat_W, const float* __restrict__ feat_b,
    const float* __restrict__ wc_W, const float* __restrict__ wc_b,
    const float* __restrict__ b_ih, const float* __restrict__ b_hh,
    float* __restrict__ ws, float* __restrict__ out)
{
  const int g = blockIdx.x;
  const int tid = threadIdx.x;   // = batch row in inner loops

  float* AT  = ws + OFF_AT;
  float* hA  = ws + OFF_HA;
  float* hB  = ws + OFF_HB;
  float* cT  = ws + OFF_CT;
  float* num = ws + OFF_NUM;
  float* den = ws + OFF_DEN;
  unsigned* bar = (unsigned*)(ws + OFF_BAR);
  float* xhT = ws + OFF_XH;
  float* xcT = ws + OFF_XC;
  float* gxT = ws + OFF_GX;
  const float* Wg = ws + OFF_WG;

  // ---- LDS: all time-invariant weights staged ONCE (immune to the barrier
  // fences' L2 invalidation that caused the 805 MB/dispatch HBM re-fetch) ----
  __shared__ float lsW[768 * 8];     // gate weights, [k][u0:i,f,g,o | u1:i,f,g,o]
  __shared__ float lsTdh[2 * F];     // td_h_W rows j0, j1
  __shared__ float lsHist[H];        // hist_W row g      (g < F)
  __shared__ float lsFeat[F];        // feat_W row g      (g < F)
  __shared__ float lsWc[2 * F];      // wc_W row g        (g < F)
  __shared__ float redA[4], redB[4];

  const int j0 = 2 * g, j1 = 2 * g + 1;   // this block's H units (P4)

  {
    const float4* Wg4 = (const float4*)Wg;
    float4* lsW4 = (float4*)lsW;
    for (int k = tid; k < 768; k += 256) {
      lsW4[2 * k]     = Wg4[(size_t)j0 * 768 + k];
      lsW4[2 * k + 1] = Wg4[(size_t)j1 * 768 + k];
    }
    if (tid < F) {
      lsTdh[tid]     = td_h_W[(size_t)j0 * F + tid];
      lsTdh[F + tid] = td_h_W[(size_t)j1 * F + tid];
    }
    if (g < F) {
      for (int k = tid; k < H; k += 256) lsHist[k] = hist_W[(size_t)g * H + k];
      if (tid < F) lsFeat[tid] = feat_W[(size_t)g * F + tid];
      lsWc[tid] = wc_W[(size_t)g * (2 * F) + tid];
    }
  }
  __syncthreads();

  for (int t = 0; t < T; ++t) {
    const float* hRd = (t & 1) ? hB : hA;   // decayed h(t), written by P4(t-1)
    float*       hWr = (t & 1) ? hA : hB;

    grid_bar(bar);   // h(t) fully published

    // ---------- P2: x_hist, x_c, gamma_x, m^T, loss term 1, denom ----------
    if (g < F) {
      const int f = g;
      float acc = hist_b[f];
#pragma unroll 8
      for (int k = 0; k < H; ++k) acc = fmaf(hRd[k * B + tid], lsHist[k], acc);
      const int idx = (tid * T + t) * F + f;
      const float mv = m[idx], xv = x[idx], dv = d[idx];
      xhT[f * B + tid] = acc;
      const float xc = mv * xv + (1.f - mv) * acc;
      xcT[f * B + tid] = xc;
      gxT[f * B + tid] = __expf(-fmaxf(fmaf(dv, td_x_W[f * F + f], td_x_b[f]), 0.f));
      AT[(F + f) * B + tid] = mv;
      const float ev = tmask[idx], tg = tx[idx];
      const float d1 = acc - tg;
      float s1 = wave_sum(d1 * d1 * ev), s2 = wave_sum(ev);
      if ((tid & 63) == 0) { redA[tid >> 6] = s1; redB[tid >> 6] = s2; }
      __syncthreads();
      if (tid == 0) {
        atomicAdd(&num[t], redA[0] + redA[1] + redA[2] + redA[3]);
        atomicAdd(&den[t], redB[0] + redB[1] + redB[2] + redB[3]);
      }
    }

    grid_bar(bar);   // x_c complete

    // ---------- P3: z_h, alpha, c_h, c_c (imputation), loss terms 2+3 ----------
    if (g < F) {
      const int f = g;
      float acc = feat_b[f];
#pragma unroll 8
      for (int k = 0; k < F; ++k) acc = fmaf(xcT[k * B + tid], lsFeat[k], acc);
      acc -= xcT[f * B + tid] * lsFeat[f];       // diagonal mask
      const float zh = acc;
      float aacc = wc_b[f];
#pragma unroll 8
      for (int k = 0; k < F; ++k) {
        aacc = fmaf(gxT[k * B + tid], lsWc[k], aacc);
        aacc = fmaf(AT[(F + k) * B + tid], lsWc[F + k], aacc);
      }
      const float al = fast_sig(aacc);
      const float xh = xhT[f * B + tid];
      const float ch = al * zh + (1.f - al) * xh;
      const int idx = (tid * T + t) * F + f;
      const float mv = AT[(F + f) * B + tid];
      const float cc = mv * x[idx] + (1.f - mv) * ch;
      AT[f * B + tid] = cc;
      out[idx] = cc;                              // imputation
      const float ev = tmask[idx], tg = tx[idx];
      const float d2 = zh - tg, d3 = ch - tg;
      float s = wave_sum((d2 * d2 + d3 * d3) * ev);
      if ((tid & 63) == 0) redA[tid >> 6] = s;
      __syncthreads();
      if (tid == 0) atomicAdd(&num[t], redA[0] + redA[1] + redA[2] + redA[3]);
    }

    grid_bar(bar);   // c_c complete

    // ---------- P4: gates (K=768, weights in LDS), LSTM update, next decay ----------
    {
      const float4* w4 = (const float4*)lsW;
      float a0i = b_ih[j0] + b_hh[j0];
      float a0f = b_ih[H + j0] + b_hh[H + j0];
      float a0g = b_ih[2 * H + j0] + b_hh[2 * H + j0];
      float a0o = b_ih[3 * H + j0] + b_hh[3 * H + j0];
      float a1i = b_ih[j1] + b_hh[j1];
      float a1f = b_ih[H + j1] + b_hh[H + j1];
      float a1g = b_ih[2 * H + j1] + b_hh[2 * H + j1];
      float a1o = b_ih[3 * H + j1] + b_hh[3 * H + j1];
#pragma unroll 4
      for (int k = 0; k < 2 * F; ++k) {          // [c_c | m] part
        const float a = AT[k * B + tid];
        const float4 w0 = w4[2 * k], w1 = w4[2 * k + 1];
        a0i = fmaf(a, w0.x, a0i); a0f = fmaf(a, w0.y, a0f);
        a0g = fmaf(a, w0.z, a0g); a0o = fmaf(a, w0.w, a0o);
        a1i = fmaf(a, w1.x, a1i); a1f = fmaf(a, w1.y, a1f);
        a1g = fmaf(a, w1.z, a1g); a1o = fmaf(a, w1.w, a1o);
      }
#pragma unroll 4
      for (int k = 0; k < H; ++k) {              // h part
        const float a = hRd[k * B + tid];
        const float4 w0 = w4[2 * (2 * F + k)], w1 = w4[2 * (2 * F + k) + 1];
        a0i = fmaf(a, w0.x, a0i); a0f = fmaf(a, w0.y, a0f);
        a0g = fmaf(a, w0.z, a0g); a0o = fmaf(a, w0.w, a0o);
        a1i = fmaf(a, w1.x, a1i); a1f = fmaf(a, w1.y, a1f);
        a1g = fmaf(a, w1.z, a1g); a1o = fmaf(a, w1.w, a1o);
      }
      // gamma_h(t+1) for own units (enables h double-buffer)
      const int t2 = (t + 1 < T) ? (t + 1) : t;
      const float* drow = d + (tid * T + t2) * F;
      float g0acc = td_h_b[j0], g1acc = td_h_b[j1];
#pragma unroll 8
      for (int k = 0; k < F; ++k) {
        const float dv = drow[k];
        g0acc = fmaf(dv, lsTdh[k], g0acc);
        g1acc = fmaf(dv, lsTdh[F + k], g1acc);
      }
      const float gam0 = __expf(-fmaxf(g0acc, 0.f));
      const float gam1 = __expf(-fmaxf(g1acc, 0.f));
      {
        const float ig = fast_sig(a0i), fg = fast_sig(a0f);
        const float gg = fast_tanh(a0g), og = fast_sig(a0o);
        const float cn = fg * cT[j0 * B + tid] + ig * gg;
        const float hn = og * fast_tanh(cn);
        cT[j0 * B + tid] = cn;
        hWr[j0 * B + tid] = hn * gam0;           // store pre-decayed h(t+1)
      }
      {
        const float ig = fast_sig(a1i), fg = fast_sig(a1f);
        const float gg = fast_tanh(a1g), og = fast_sig(a1o);
        const float cn = fg * cT[j1 * B + tid] + ig * gg;
        const float hn = og * fast_tanh(cn);
        cT[j1 * B + tid] = cn;
        hWr[j1 * B + tid] = hn * gam1;
      }
    }
  }

  grid_bar(bar);
  if (g == 0 && tid == 0) {
    float L = 0.f;
    for (int t = 0; t < T; ++t) L += num[t] / (den[t] + 1e-8f);
    out[(size_t)B * T * F] = L / (float)T;
  }
}

extern "C" void kernel_launch(void* const* d_in, const int* in_sizes, int n_in,
                              void* d_out, int out_size, void* d_ws, size_t ws_size,
                              hipStream_t stream) {
  const float* x      = (const float*)d_in[0];
  const float* m      = (const float*)d_in[1];
  const float* d      = (const float*)d_in[2];
  const float* tx     = (const float*)d_in[3];
  const float* tmask  = (const float*)d_in[4];
  const float* td_h_W = (const float*)d_in[5];
  const float* td_h_b = (const float*)d_in[6];
  const float* td_x_W = (const float*)d_in[7];
  const float* td_x_b = (const float*)d_in[8];
  const float* hist_W = (const float*)d_in[9];
  const float* hist_b = (const float*)d_in[10];
  const float* feat_W = (const float*)d_in[11];
  const float* feat_b = (const float*)d_in[12];
  const float* wc_W   = (const float*)d_in[13];
  const float* wc_b   = (const float*)d_in[14];
  const float* W_ih   = (const float*)d_in[15];
  const float* W_hh   = (const float*)d_in[16];
  const float* b_ih   = (const float*)d_in[17];
  const float* b_hh   = (const float*)d_in[18];

  float* ws  = (float*)d_ws;
  float* out = (float*)d_out;

  // Tripwire: avoid OOB workspace writes (would kill the container).
  if (ws_size < WS_FLOATS * sizeof(float)) return;

  hipMemsetAsync(d_ws, 0, ZERO_BYTES, stream);
  prep_wg<<<dim3(H), dim3(256), 0, stream>>>(W_ih, W_hh, ws + OFF_WG);
  rits_main<<<dim3(NBLK), dim3(256), 0, stream>>>(
      x, m, d, tx, tmask, td_h_W, td_h_b, td_x_W, td_x_b,
      hist_W, hist_b, feat_W, feat_b, wc_W, wc_b, b_ih, b_hh, ws, out);
}

// Round 4
// 4601.743 us; speedup vs baseline: 3.9859x; 3.3350x over previous
//
#include <hip/hip_runtime.h>

#define DEVINL __device__ __forceinline__

namespace {
constexpr int B = 256, T = 128, F = 128, H = 512;
constexpr int NBLK = 128;        // 2 batch rows per block, no cross-block deps

// workspace layout in 4-byte words
constexpr size_t OFF_NUM   = 0;                      // [T] loss numerators (f32)
constexpr size_t OFF_DEN   = OFF_NUM + T;            // [T] denominators
constexpr size_t OFF_WG2   = 256;                    // gate W f16x2 [384 k2][2048 col]
constexpr size_t OFF_TD2   = OFF_WG2 + 384 * 2048;   // td_h  f16x2 [64 k2][512 j]
constexpr size_t OFF_HIST2 = OFF_TD2 + 64 * 512;     // hist  f16x2 [256 k2][128 f]
constexpr size_t OFF_FEAT2 = OFF_HIST2 + 256 * 128;  // feat  f16x2 [64 k2][128 f]
constexpr size_t OFF_WC2   = OFF_FEAT2 + 64 * 128;   // wc    f16x2 [128 k2][128 f]
constexpr size_t OFF_BSUM  = OFF_WC2 + 128 * 128;    // [2048] b_ih+b_hh, gate-interleaved (f32)
constexpr size_t OFF_FDIAG = OFF_BSUM + 2048;        // [128] f16-rounded feat diag (f32)
constexpr size_t WS_WORDS  = OFF_FDIAG + 128;        // ~3.5 MB
}

typedef _Float16 h2_t __attribute__((ext_vector_type(2)));

DEVINL h2_t as_h2(unsigned u) { union { unsigned u; h2_t h; } c; c.u = u; return c.h; }
DEVINL unsigned pack2(float a, float b) {
  union { h2_t h; unsigned u; } c;
  c.h = h2_t{(_Float16)a, (_Float16)b};
  return c.u;
}

#if defined(__has_builtin)
#if __has_builtin(__builtin_amdgcn_fdot2)
#define HAVE_FDOT2 1
#endif
#endif
#ifdef HAVE_FDOT2
DEVINL float fdot2(h2_t a, h2_t b, float c) { return __builtin_amdgcn_fdot2(a, b, c, false); }
#else
DEVINL float fdot2(h2_t a, h2_t b, float c) {
  return fmaf((float)a.x, (float)b.x, fmaf((float)a.y, (float)b.y, c));
}
#endif

DEVINL float fast_sig(float x)  { return 1.f / (1.f + __expf(-x)); }
DEVINL float fast_tanh(float x) { return 1.f - 2.f / (1.f + __expf(2.f * x)); }

DEVINL float wave_sum(float v) {
#pragma unroll
  for (int s = 32; s; s >>= 1) v += __shfl_down(v, s, 64);
  return v;
}

// ---- prep: pack gate weights [k2][unit*4+gate] f16x2 (gate-interleaved) ----
__global__ void prep_gates(const float* __restrict__ Wih, const float* __restrict__ Whh,
                           unsigned* __restrict__ wg2) {
  int idx = blockIdx.x * blockDim.x + threadIdx.x;
  if (idx >= 384 * 2048) return;
  const int k2 = idx >> 11, col = idx & 2047, unit = col >> 2, g = col & 3;
  const int row = g * 512 + unit, k0 = 2 * k2;
  float w0, w1;
  if (k0 < 256) { w0 = Wih[row * 256 + k0]; w1 = Wih[row * 256 + k0 + 1]; }
  else          { w0 = Whh[row * 512 + k0 - 256]; w1 = Whh[row * 512 + k0 - 255]; }
  wg2[idx] = pack2(w0, w1);
}

__global__ void prep_small(const float* __restrict__ td_h_W, const float* __restrict__ hist_W,
                           const float* __restrict__ feat_W, const float* __restrict__ wc_W,
                           const float* __restrict__ b_ih, const float* __restrict__ b_hh,
                           unsigned* __restrict__ wsu, float* __restrict__ wsf) {
  int idx = blockIdx.x * blockDim.x + threadIdx.x;
  if (idx < 32768) {                       // TD2 [64][512]
    int k2 = idx >> 9, j = idx & 511;
    wsu[OFF_TD2 + idx] = pack2(td_h_W[j * 128 + 2 * k2], td_h_W[j * 128 + 2 * k2 + 1]);
  } else if (idx < 65536) {                // HIST2 [256][128]
    int i = idx - 32768; int k2 = i >> 7, f = i & 127;
    wsu[OFF_HIST2 + i] = pack2(hist_W[f * 512 + 2 * k2], hist_W[f * 512 + 2 * k2 + 1]);
  } else if (idx < 73728) {                // FEAT2 [64][128]
    int i = idx - 65536; int k2 = i >> 7, f = i & 127;
    wsu[OFF_FEAT2 + i] = pack2(feat_W[f * 128 + 2 * k2], feat_W[f * 128 + 2 * k2 + 1]);
  } else if (idx < 90112) {                // WC2 [128][128]
    int i = idx - 73728; int k2 = i >> 7, f = i & 127;
    wsu[OFF_WC2 + i] = pack2(wc_W[f * 256 + 2 * k2], wc_W[f * 256 + 2 * k2 + 1]);
  } else if (idx < 92160) {                // BSUM [2048]
    int i = idx - 90112; int unit = i >> 2, g = i & 3;
    wsf[OFF_BSUM + i] = b_ih[g * 512 + unit] + b_hh[g * 512 + unit];
  } else if (idx < 92288) {                // FDIAG [128] (match f16-rounded dot term)
    int f = idx - 92160;
    wsf[OFF_FDIAG + f] = (float)(_Float16)feat_W[f * 128 + f];
  }
}

// ---- main: each block owns 2 batch rows end-to-end; h,c live in LDS ----
__global__ void __launch_bounds__(512) rits_batch(
    const float* __restrict__ x, const float* __restrict__ m, const float* __restrict__ d,
    const float* __restrict__ tx, const float* __restrict__ tmask,
    const float* __restrict__ td_h_b, const float* __restrict__ td_x_W,
    const float* __restrict__ td_x_b, const float* __restrict__ hist_b,
    const float* __restrict__ feat_b, const float* __restrict__ wc_b,
    const unsigned* __restrict__ wsu, const float* __restrict__ wsf,
    float* __restrict__ num, float* __restrict__ den, float* __restrict__ out)
{
  const int tid = threadIdx.x;               // unit id for gates; r*128+f for F-phases
  const int row0 = blockIdx.x * 2;

  __shared__ float h_ls[2 * 512], c_ls[2 * 512];
  __shared__ unsigned act2[2 * 384];         // gates input pairs: [cc(64)|m(64)|h(256)] per row
  __shared__ unsigned d2_ls[2 * 64], xc2[2 * 64], gxm2[2 * 128];
  __shared__ float xrow[256], mrow[256], drow[256], txrow[256], evrow[256];
  __shared__ float xh_ls[256], xc_ls[256], gx_ls[256], cc_ls[256];
  __shared__ float redA[8], redB[8];

  // persistent per-thread constants
  const float4 bs = *(const float4*)(wsf + OFF_BSUM + 4 * tid);
  const float tdb = td_h_b[tid];
  float hb = 0, fb = 0, wb = 0, fd = 0, dxw = 0, dxb = 0;
  if (tid < 256) {
    const int f = tid & 127;
    hb = hist_b[f]; fb = feat_b[f]; wb = wc_b[f];
    fd = wsf[OFF_FDIAG + f]; dxw = td_x_W[f * 129]; dxb = td_x_b[f];
  }
  h_ls[tid] = 0.f; h_ls[512 + tid] = 0.f;
  c_ls[tid] = 0.f; c_ls[512 + tid] = 0.f;
  __syncthreads();

  const unsigned* WG2 = wsu + OFF_WG2 + 4 * tid;

  for (int t = 0; t < T; ++t) {
    // ---- A: load input rows (tid<256: r=tid>>7, f=tid&127) + d pairs (tid<128) ----
    if (tid < 256) {
      const int r = tid >> 7, f = tid & 127;
      const int idx = ((row0 + r) * T + t) * F + f;
      xrow[tid] = x[idx]; mrow[tid] = m[idx]; drow[tid] = d[idx];
      txrow[tid] = tx[idx]; evrow[tid] = tmask[idx];
    } else if (tid < 384) {
      const int i = tid - 256, r = i >> 6, k2 = i & 63;   // no LDS dep: read global
      const int base = ((row0 + r) * T + t) * F;
      d2_ls[i] = pack2(d[base + 2 * k2], d[base + 2 * k2 + 1]);
    }
    __syncthreads();

    // ---- C: gamma_h (unit=tid, both rows) + decay h in place ----
    {
      float g0 = tdb, g1 = tdb;
#pragma unroll 8
      for (int k2 = 0; k2 < 64; ++k2) {
        const h2_t w = as_h2(wsu[OFF_TD2 + (k2 << 9) + tid]);
        g0 = fdot2(w, as_h2(d2_ls[k2]), g0);
        g1 = fdot2(w, as_h2(d2_ls[64 + k2]), g1);
      }
      h_ls[tid]       *= __expf(-fmaxf(g0, 0.f));
      h_ls[512 + tid] *= __expf(-fmaxf(g1, 0.f));
    }
    __syncthreads();

    // ---- D: pack decayed h into gates-input pairs ----
    {
      const int r = tid >> 8, k2 = tid & 255;
      act2[r * 384 + 128 + k2] = pack2(h_ls[r * 512 + 2 * k2], h_ls[r * 512 + 2 * k2 + 1]);
    }
    __syncthreads();

    // ---- E: x_hist (K=512 dot2), gamma_x, x_c ----
    if (tid < 256) {
      const int r = tid >> 7, f = tid & 127;
      float acc = hb;
      const unsigned* hp = wsu + OFF_HIST2 + f;
      const unsigned* ap = (const unsigned*)act2 + r * 384 + 128;
#pragma unroll 8
      for (int k2 = 0; k2 < 256; ++k2)
        acc = fdot2(as_h2(hp[k2 << 7]), as_h2(ap[k2]), acc);
      xh_ls[tid] = acc;
      const float gx = __expf(-fmaxf(fmaf(drow[tid], dxw, dxb), 0.f));
      gx_ls[tid] = gx;
      const float mv = mrow[tid];
      xc_ls[tid] = mv * xrow[tid] + (1.f - mv) * acc;
    }
    __syncthreads();

    // ---- F: pack xc pairs and [gamma_x|m] pairs ----
    if (tid < 128) {
      const int r = tid >> 6, k2 = tid & 63;
      xc2[tid] = pack2(xc_ls[r * 128 + 2 * k2], xc_ls[r * 128 + 2 * k2 + 1]);
    } else if (tid < 384) {
      const int i = tid - 128, r = i >> 7, q = i & 127;
      gxm2[i] = (q < 64) ? pack2(gx_ls[r * 128 + 2 * q], gx_ls[r * 128 + 2 * q + 1])
                         : pack2(mrow[r * 128 + 2 * (q - 64)], mrow[r * 128 + 2 * (q - 64) + 1]);
    }
    __syncthreads();

    // ---- G: z_h, alpha, c_h, c_c, imputation write, loss partials ----
    float lt = 0.f, le = 0.f;
    if (tid < 256) {
      const int r = tid >> 7, f = tid & 127;
      float z = fb;
      const unsigned* fp = wsu + OFF_FEAT2 + f;
      const unsigned* xp = (const unsigned*)xc2 + r * 64;
#pragma unroll 8
      for (int k2 = 0; k2 < 64; ++k2)
        z = fdot2(as_h2(fp[k2 << 7]), as_h2(xp[k2]), z);
      z -= xc_ls[tid] * fd;                       // remove diagonal (same f16 values)
      float aa = wb;
      const unsigned* wp = wsu + OFF_WC2 + f;
      const unsigned* gp = (const unsigned*)gxm2 + r * 128;
#pragma unroll 8
      for (int k2 = 0; k2 < 128; ++k2)
        aa = fdot2(as_h2(wp[k2 << 7]), as_h2(gp[k2]), aa);
      const float al = fast_sig(aa);
      const float xh = xh_ls[tid];
      const float ch = al * z + (1.f - al) * xh;
      const float mv = mrow[tid];
      const float cc = mv * xrow[tid] + (1.f - mv) * ch;
      cc_ls[tid] = cc;
      out[((row0 + r) * T + t) * F + f] = cc;
      const float ev = evrow[tid], tg = txrow[tid];
      const float e1 = xh - tg, e2 = z - tg, e3 = ch - tg;
      lt = ev * (e1 * e1 + e2 * e2 + e3 * e3);
      le = ev;
      const float s1 = wave_sum(lt), s2 = wave_sum(le);
      if ((tid & 63) == 0) { redA[tid >> 6] = s1; redB[tid >> 6] = s2; }
    }
    __syncthreads();

    // ---- H: pack [cc|m] pairs + one atomic pair per block ----
    if (tid < 256) {
      const int r = tid >> 7, q = tid & 127;
      act2[r * 384 + q] = (q < 64)
          ? pack2(cc_ls[r * 128 + 2 * q], cc_ls[r * 128 + 2 * q + 1])
          : pack2(mrow[r * 128 + 2 * (q - 64)], mrow[r * 128 + 2 * (q - 64) + 1]);
    } else if (tid == 500) {
      atomicAdd(&num[t], redA[0] + redA[1] + redA[2] + redA[3]);
      atomicAdd(&den[t], redB[0] + redB[1] + redB[2] + redB[3]);
    }
    __syncthreads();

    // ---- I: gates GEMV (K=768 as 384 f16x2), LSTM update ----
    {
      float a0i = bs.x, a0f = bs.y, a0g = bs.z, a0o = bs.w;
      float a1i = bs.x, a1f = bs.y, a1g = bs.z, a1o = bs.w;
#pragma unroll 4
      for (int k2 = 0; k2 < 384; ++k2) {
        const uint4 w = *(const uint4*)(WG2 + (k2 << 11));
        const h2_t a0 = as_h2(act2[k2]);
        const h2_t a1 = as_h2(act2[384 + k2]);
        a0i = fdot2(as_h2(w.x), a0, a0i); a0f = fdot2(as_h2(w.y), a0, a0f);
        a0g = fdot2(as_h2(w.z), a0, a0g); a0o = fdot2(as_h2(w.w), a0, a0o);
        a1i = fdot2(as_h2(w.x), a1, a1i); a1f = fdot2(as_h2(w.y), a1, a1f);
        a1g = fdot2(as_h2(w.z), a1, a1g); a1o = fdot2(as_h2(w.w), a1, a1o);
      }
      {
        const float ig = fast_sig(a0i), fg = fast_sig(a0f);
        const float gg = fast_tanh(a0g), og = fast_sig(a0o);
        const float cn = fg * c_ls[tid] + ig * gg;
        c_ls[tid] = cn; h_ls[tid] = og * fast_tanh(cn);
      }
      {
        const float ig = fast_sig(a1i), fg = fast_sig(a1f);
        const float gg = fast_tanh(a1g), og = fast_sig(a1o);
        const float cn = fg * c_ls[512 + tid] + ig * gg;
        c_ls[512 + tid] = cn; h_ls[512 + tid] = og * fast_tanh(cn);
      }
    }
    __syncthreads();   // protect act2/h from next step's writers
  }
}

__global__ void finalize(const float* __restrict__ num, const float* __restrict__ den,
                         float* __restrict__ out) {
  __shared__ float red[2];
  const int t = threadIdx.x;     // 128 threads
  float v = num[t] / (den[t] + 1e-8f);
  v = wave_sum(v);
  if ((t & 63) == 0) red[t >> 6] = v;
  __syncthreads();
  if (t == 0) out[(size_t)B * T * F] = (red[0] + red[1]) / (float)T;
}

extern "C" void kernel_launch(void* const* d_in, const int* in_sizes, int n_in,
                              void* d_out, int out_size, void* d_ws, size_t ws_size,
                              hipStream_t stream) {
  const float* x      = (const float*)d_in[0];
  const float* m      = (const float*)d_in[1];
  const float* d      = (const float*)d_in[2];
  const float* tx     = (const float*)d_in[3];
  const float* tmask  = (const float*)d_in[4];
  const float* td_h_W = (const float*)d_in[5];
  const float* td_h_b = (const float*)d_in[6];
  const float* td_x_W = (const float*)d_in[7];
  const float* td_x_b = (const float*)d_in[8];
  const float* hist_W = (const float*)d_in[9];
  const float* hist_b = (const float*)d_in[10];
  const float* feat_W = (const float*)d_in[11];
  const float* feat_b = (const float*)d_in[12];
  const float* wc_W   = (const float*)d_in[13];
  const float* wc_b   = (const float*)d_in[14];
  const float* W_ih   = (const float*)d_in[15];
  const float* W_hh   = (const float*)d_in[16];
  const float* b_ih   = (const float*)d_in[17];
  const float* b_hh   = (const float*)d_in[18];

  float*    wsf = (float*)d_ws;
  unsigned* wsu = (unsigned*)d_ws;
  float*    out = (float*)d_out;

  if (ws_size < WS_WORDS * 4) return;   // OOB tripwire

  hipMemsetAsync(d_ws, 0, 2 * T * sizeof(float), stream);   // num/den
  prep_gates<<<dim3((384 * 2048 + 255) / 256), dim3(256), 0, stream>>>(W_ih, W_hh, wsu + OFF_WG2);
  prep_small<<<dim3((92288 + 255) / 256), dim3(256), 0, stream>>>(
      td_h_W, hist_W, feat_W, wc_W, b_ih, b_hh, wsu, wsf);
  rits_batch<<<dim3(NBLK), dim3(512), 0, stream>>>(
      x, m, d, tx, tmask, td_h_b, td_x_W, td_x_b, hist_b, feat_b, wc_b,
      wsu, wsf, wsf + OFF_NUM, wsf + OFF_DEN, out);
  finalize<<<dim3(1), dim3(128), 0, stream>>>(wsf + OFF_NUM, wsf + OFF_DEN, out);
}